// Round 7
// baseline (47.027 us; speedup 1.0000x reference)
//
#include <hip/hip_runtime.h>
#include <hip/hip_bf16.h>

typedef __attribute__((ext_vector_type(8)))  short bf16x8;
typedef __attribute__((ext_vector_type(16))) float f32x16;

#define I_N 256
#define T_N 256
#define L_N 32
#define E_N 128
#define P_N 49
#define TG  4   // texts per LDS buffer: 4 * 8 frags * 1KB = 32 KB/buffer

// ---- pre-pass: pack text(B) + image(A) into 32x32x16 MFMA fragment order ----
// B frag [t*8+ks][lane][8]: col l = lane&31 (token), k = ks*16 + (lane>>5)*8 + j
// A frag [i*16 + pt*8 + ks][lane][8]: patch = pt*32 + (lane&31), same k map.
__global__ __launch_bounds__(256) void pack_all(const float* __restrict__ txt,
                                                const float* __restrict__ img,
                                                unsigned short* __restrict__ bpre,
                                                unsigned short* __restrict__ apre) {
    const int bid = blockIdx.x;
    if (bid < 512) {                                 // ---- text
        int gid  = bid * 256 + threadIdx.x;
        int lane = gid & 63;
        int ks   = (gid >> 6) & 7;
        int t    = gid >> 9;
        int l    = lane & 31;
        int e0   = ks * 16 + (lane >> 5) * 8;
        const float* src = txt + (t * L_N + l) * E_N + e0;
        union { unsigned short u[8]; bf16x8 v; } o;
        #pragma unroll
        for (int j = 0; j < 8; ++j) {
            __hip_bfloat16 h = __float2bfloat16(src[j]);
            o.u[j] = *reinterpret_cast<unsigned short*>(&h);
        }
        ((bf16x8*)bpre)[gid] = o.v;
    } else {                                         // ---- image
        int gid   = (bid - 512) * 256 + threadIdx.x;
        int lane  = gid & 63;
        int ks    = (gid >> 6) & 7;
        int pt    = (gid >> 9) & 1;
        int i     = gid >> 10;
        int patch = pt * 32 + (lane & 31);
        int e0    = ks * 16 + (lane >> 5) * 8;
        const float* src = img + i * (E_N * P_N) + e0 * P_N + patch;
        union { unsigned short u[8]; bf16x8 v; } o;
        #pragma unroll
        for (int j = 0; j < 8; ++j) {
            float x = (patch < P_N) ? src[j * P_N] : 0.0f;
            __hip_bfloat16 h = __float2bfloat16(x);
            o.u[j] = *reinterpret_cast<unsigned short*>(&h);
        }
        ((bf16x8*)apre)[gid] = o.v;
    }
}

// ---- main kernel: grid (16,64), block 256 = 4 waves. Wave w -> image y*4+w. ----
// 2 blocks/CU; each SIMD hosts 2 waves from DIFFERENT blocks (independent phases).
// Per-text pipeline: mfma(tx) -> prefetch bf(tx+1) -> reduce(tx-1), so ds_read
// latency and the serial shuffle-reduce both hide under the MFMA drain.
__global__ __launch_bounds__(256) void clip_mfma(
    const unsigned short* __restrict__ apre,
    const unsigned short* __restrict__ bpre,
    const int*   __restrict__ tlen,
    const float* __restrict__ nlt,
    float*       __restrict__ out) {

    __shared__ short sB[2][TG * 8 * 512];   // 2 x 32 KB; group g lives in buf g&1

    const int wid  = threadIdx.x >> 6;
    const int lane = threadIdx.x & 63;
    const int i    = blockIdx.y * 4 + wid;
    const int t0   = blockIdx.x * 16;
    const float scale = expf(nlt[0]);
    const bool  lo32  = (lane < 32);

    // Pin image A-frags: 2 patch-tiles x 8 k-steps = 64 VGPRs, reused for 16 texts.
    bf16x8 af[2][8];
    const bf16x8* ap = (const bf16x8*)apre + (size_t)i * 16 * 64;
    #pragma unroll
    for (int pt = 0; pt < 2; ++pt)
        #pragma unroll
        for (int ks = 0; ks < 8; ++ks)
            af[pt][ks] = ap[(pt * 8 + ks) * 64 + lane];

    // Stage B-frags for texts [t0+g*TG, +TG) into buf: 32 frags, wave does 8.
    auto stage = [&](int buf, int g) {
        #pragma unroll
        for (int q = 0; q < 8; ++q) {
            int fl = wid * 8 + q;                   // 0..31 = t_in_group*8 + ks
            int t  = t0 + g * TG + (fl >> 3);
            int f  = fl & 7;
            const unsigned short* src = bpre + ((size_t)(t * 8 + f)) * 512 + lane * 8;
            short* dst = &sB[buf][fl * 512];
            __builtin_amdgcn_global_load_lds(
                (const __attribute__((address_space(1))) unsigned int*)(const void*)src,
                (__attribute__((address_space(3))) unsigned int*)(void*)dst, 16, 0, 0);
        }
    };

    auto loadB = [&](bf16x8 (&bf)[8], int buf, int txg) {
        const bf16x8* bfp = (const bf16x8*)&sB[buf][0];
        #pragma unroll
        for (int ks = 0; ks < 8; ++ks)
            bf[ks] = bfp[(txg * 8 + ks) * 64 + lane];
    };

    auto mfmaT = [&](f32x16 (&acc)[2], bf16x8 (&bf)[8]) {
        #pragma unroll
        for (int pt = 0; pt < 2; ++pt)
            #pragma unroll
            for (int r = 0; r < 16; ++r)
                acc[pt][r] = 0.0f;
        __builtin_amdgcn_s_setprio(1);
        #pragma unroll
        for (int ks = 0; ks < 8; ++ks)
            #pragma unroll
            for (int pt = 0; pt < 2; ++pt)
                acc[pt] = __builtin_amdgcn_mfma_f32_32x32x16_bf16(
                    af[pt][ks], bf[ks], acc[pt], 0, 0, 0);
        __builtin_amdgcn_s_setprio(0);
    };

    // Reduce one text: max over 49 patches, sum over 32 tokens.
    // C: col = lane&31 (token), row = (reg&3)+8*(reg>>2)+4*(lane>>5) (patch in tile).
    // Tile1 (patches 32..63): regs 0..7 valid both halves; reg 8 lo-half only (p=48).
    auto reduceT = [&](f32x16 (&a)[2], int t) {
        float m = a[0][0];
        #pragma unroll
        for (int r = 1; r < 16; ++r) m = fmaxf(m, a[0][r]);
        #pragma unroll
        for (int r = 0; r < 8; ++r)  m = fmaxf(m, a[1][r]);
        m = fmaxf(m, lo32 ? a[1][8] : -INFINITY);
        m = fmaxf(m, __shfl_xor(m, 32));            // merge lane halves -> 49-patch max
        float s = m;
        #pragma unroll
        for (int off = 1; off <= 16; off <<= 1)
            s += __shfl_xor(s, off);                // sum over 32 token cols
        if (lane == 0) {
            float match = (s / (float)tlen[t]) * scale;
            out[i * T_N + t]             = match;   // logits_per_image [I][T]
            out[I_N * T_N + t * I_N + i] = match;   // logits_per_text  [T][I]
        }
    };

    bf16x8 bfA[8], bfB[8];
    f32x16 accA[2], accB[2];

    // Prologue: stage groups 0 and 1; barrier drains both; load text 0's frags.
    stage(0, 0);
    stage(1, 1);
    __syncthreads();
    loadB(bfA, 0, 0);

    // Slot tx: compute tx (frags pre-loaded), prefetch tx+1, reduce tx-1.
    // Group boundary (txg==3): barrier (stage g+1 complete; buf g&1 reads done),
    // refill buf g&1 with group g+2, then load next group's first text.
    auto slot = [&](int tx, bf16x8 (&bfC)[8], f32x16 (&accC)[2],
                    bf16x8 (&bfN)[8], f32x16 (&accP)[2]) {
        const int g   = tx >> 2;
        const int txg = tx & 3;
        mfmaT(accC, bfC);
        if (txg < 3) loadB(bfN, g & 1, txg + 1);      // prefetch under MFMA drain
        if (tx > 0)  reduceT(accP, t0 + tx - 1);      // prev text, other parity
        if (txg == 3 && tx + 1 < 16) {
            __syncthreads();
            if (g + 2 < 4) stage(g & 1, g + 2);       // refill just-freed buffer
            loadB(bfN, (g + 1) & 1, 0);               // first text of next group
        }
    };

    #pragma unroll
    for (int pr = 0; pr < 8; ++pr) {
        slot(2 * pr,     bfA, accA, bfB, accB);
        slot(2 * pr + 1, bfB, accB, bfA, accA);
    }
    reduceT(accB, t0 + 15);   // tx=15 computed into accB
}

extern "C" void kernel_launch(void* const* d_in, const int* in_sizes, int n_in,
                              void* d_out, int out_size, void* d_ws, size_t ws_size,
                              hipStream_t stream) {
    const float* img  = (const float*)d_in[0];
    const float* txt  = (const float*)d_in[1];
    const int*   tlen = (const int*)d_in[2];
    const float* nlt  = (const float*)d_in[3];
    float*       out  = (float*)d_out;

    unsigned short* bpre = (unsigned short*)d_ws;                       // 2 MB
    unsigned short* apre = (unsigned short*)((char*)d_ws + (2u << 20)); // 4 MB

    pack_all<<<1536, 256, 0, stream>>>(txt, img, bpre, apre);

    dim3 grid(16, 64);
    clip_mfma<<<grid, 256, 0, stream>>>(apre, bpre, tlen, nlt, out);
}

// Round 8
// 46.903 us; speedup vs baseline: 1.0026x; 1.0026x over previous
//
#include <hip/hip_runtime.h>
#include <hip/hip_bf16.h>

typedef __attribute__((ext_vector_type(8)))  short bf16x8;
typedef __attribute__((ext_vector_type(16))) float f32x16;

#define I_N 256
#define T_N 256
#define L_N 32
#define E_N 128
#define P_N 49

// ---- pre-pass: pack text(B) + image(A) into 32x32x16 MFMA fragment order ----
// B frag [t*8+ks][lane][8]: col l = lane&31 (token), k = ks*16 + (lane>>5)*8 + j
// A frag [i*16 + pt*8 + ks][lane][8]: patch = pt*32 + (lane&31), same k map.
__global__ __launch_bounds__(256) void pack_all(const float* __restrict__ txt,
                                                const float* __restrict__ img,
                                                unsigned short* __restrict__ bpre,
                                                unsigned short* __restrict__ apre) {
    const int bid = blockIdx.x;
    if (bid < 512) {                                 // ---- text
        int gid  = bid * 256 + threadIdx.x;
        int lane = gid & 63;
        int ks   = (gid >> 6) & 7;
        int t    = gid >> 9;
        int l    = lane & 31;
        int e0   = ks * 16 + (lane >> 5) * 8;
        const float* src = txt + (t * L_N + l) * E_N + e0;
        union { unsigned short u[8]; bf16x8 v; } o;
        #pragma unroll
        for (int j = 0; j < 8; ++j) {
            __hip_bfloat16 h = __float2bfloat16(src[j]);
            o.u[j] = *reinterpret_cast<unsigned short*>(&h);
        }
        ((bf16x8*)bpre)[gid] = o.v;
    } else {                                         // ---- image
        int gid   = (bid - 512) * 256 + threadIdx.x;
        int lane  = gid & 63;
        int ks    = (gid >> 6) & 7;
        int pt    = (gid >> 9) & 1;
        int i     = gid >> 10;
        int patch = pt * 32 + (lane & 31);
        int e0    = ks * 16 + (lane >> 5) * 8;
        const float* src = img + i * (E_N * P_N) + e0 * P_N + patch;
        union { unsigned short u[8]; bf16x8 v; } o;
        #pragma unroll
        for (int j = 0; j < 8; ++j) {
            float x = (patch < P_N) ? src[j * P_N] : 0.0f;
            __hip_bfloat16 h = __float2bfloat16(x);
            o.u[j] = *reinterpret_cast<unsigned short*>(&h);
        }
        ((bf16x8*)apre)[gid] = o.v;
    }
}

// ---- main kernel: grid (16,64), block 256 = 4 waves, NO LDS, NO barriers. ----
// Wave w -> image blockIdx.y*4+w, texts t0..t0+15. B-frags load coalesced from
// L2-resident bpre. VGPR ~145 + launch_bounds cap 170 -> 3 waves/SIMD: each
// wave's load latency + serial reduce hides under the other two waves' MFMAs.
__global__ __launch_bounds__(256, 3) void clip_mfma(
    const unsigned short* __restrict__ apre,
    const unsigned short* __restrict__ bpre,
    const int*   __restrict__ tlen,
    const float* __restrict__ nlt,
    float*       __restrict__ out) {

    const int wid  = threadIdx.x >> 6;
    const int lane = threadIdx.x & 63;
    const int i    = blockIdx.y * 4 + wid;
    const int t0   = blockIdx.x * 16;
    const float scale = expf(nlt[0]);
    const bool  lo32  = (lane < 32);

    // Pin image A-frags: 2 patch-tiles x 8 k-steps = 64 VGPRs, reused for 16 texts.
    bf16x8 af[2][8];
    const bf16x8* ap = (const bf16x8*)apre + (size_t)i * 16 * 64;
    #pragma unroll
    for (int pt = 0; pt < 2; ++pt)
        #pragma unroll
        for (int ks = 0; ks < 8; ++ks)
            af[pt][ks] = ap[(pt * 8 + ks) * 64 + lane];

    const bf16x8* bp = (const bf16x8*)bpre;

    #pragma unroll 1
    for (int tx = 0; tx < 16; ++tx) {
        const int t = t0 + tx;

        // 8 coalesced 16B loads: wave reads 1KB contiguous per frag (L2-hot).
        bf16x8 bf[8];
        const bf16x8* tb = bp + (size_t)t * 8 * 64;
        #pragma unroll
        for (int ks = 0; ks < 8; ++ks)
            bf[ks] = tb[ks * 64 + lane];

        f32x16 a0, a1;
        #pragma unroll
        for (int r = 0; r < 16; ++r) { a0[r] = 0.0f; a1[r] = 0.0f; }

        __builtin_amdgcn_s_setprio(1);
        #pragma unroll
        for (int ks = 0; ks < 8; ++ks) {
            a0 = __builtin_amdgcn_mfma_f32_32x32x16_bf16(af[0][ks], bf[ks], a0, 0, 0, 0);
            a1 = __builtin_amdgcn_mfma_f32_32x32x16_bf16(af[1][ks], bf[ks], a1, 0, 0, 0);
        }
        __builtin_amdgcn_s_setprio(0);

        // Reduce: max over 49 patches, sum over 32 tokens.
        // C: col = lane&31 (token), row = (reg&3)+8*(reg>>2)+4*(lane>>5).
        // Tile1 (patches 32..63): regs 0..7 valid both halves; reg 8 lo-half (p=48).
        float m = a0[0];
        #pragma unroll
        for (int r = 1; r < 16; ++r) m = fmaxf(m, a0[r]);
        #pragma unroll
        for (int r = 0; r < 8; ++r)  m = fmaxf(m, a1[r]);
        m = fmaxf(m, lo32 ? a1[8] : -INFINITY);
        m = fmaxf(m, __shfl_xor(m, 32));            // merge halves -> 49-patch max
        float s = m;
        #pragma unroll
        for (int off = 1; off <= 16; off <<= 1)
            s += __shfl_xor(s, off);                // sum over 32 token cols

        if (lane == 0) {
            float match = (s / (float)tlen[t]) * scale;
            out[i * T_N + t]             = match;   // logits_per_image [I][T]
            out[I_N * T_N + t * I_N + i] = match;   // logits_per_text  [T][I]
        }
    }
}

extern "C" void kernel_launch(void* const* d_in, const int* in_sizes, int n_in,
                              void* d_out, int out_size, void* d_ws, size_t ws_size,
                              hipStream_t stream) {
    const float* img  = (const float*)d_in[0];
    const float* txt  = (const float*)d_in[1];
    const int*   tlen = (const int*)d_in[2];
    const float* nlt  = (const float*)d_in[3];
    float*       out  = (float*)d_out;

    unsigned short* bpre = (unsigned short*)d_ws;                       // 2 MB
    unsigned short* apre = (unsigned short*)((char*)d_ws + (2u << 20)); // 4 MB

    pack_all<<<1536, 256, 0, stream>>>(txt, img, bpre, apre);

    dim3 grid(16, 64);
    clip_mfma<<<grid, 256, 0, stream>>>(apre, bpre, tlen, nlt, out);
}